// Round 1
// 6282.623 us; speedup vs baseline: 1.1088x; 1.1088x over previous
//
#include <hip/hip_runtime.h>

// GTS forecasting (DCGRU enc-dec over dense 10000x10000 adjacency), gfx950.
// R3: T2 both-sides XOR swizzle on LDS tiles (gemm_bt + cellmm) to kill the
// row-stride-128B half-bank ds_read_b128 pattern, plus double-buffered LDS
// with counted vmcnt + raw barriers (T4-lite) in gemm_bt (templated on NT so
// vmcnt literals are exact per wave).

typedef unsigned short u16;
typedef __attribute__((ext_vector_type(8))) short short8;
typedef __attribute__((ext_vector_type(8))) unsigned short u16x8;
typedef __attribute__((ext_vector_type(4))) unsigned short u16x4;
typedef __attribute__((ext_vector_type(4))) float f32x4;

#define NN 10000
#define P 10112          // padded m pitch (79*128)
#define KPAD 10048       // 157*64 k-chunks
#define SPLITS 13
#define KSPLIT 768       // 12 chunks per split; last split gets 13
#define PLANE 808960     // 80*P shorts per split plane

__device__ __forceinline__ u16 f2bf(float f) {
  unsigned u = __float_as_uint(f);
  unsigned r = (u + 0x7FFFu + ((u >> 16) & 1u)) >> 16;
  return (u16)r;
}
__device__ __forceinline__ float bf2f(u16 v) {
  return __uint_as_float((unsigned)v << 16);
}

__device__ __forceinline__ void load_lds16(const void* g, void* l) {
  __builtin_amdgcn_global_load_lds(
      (__attribute__((address_space(1))) void*)(void*)g,
      (__attribute__((address_space(3))) void*)l, 16, 0, 0);
}

// ---------------- fp32 -> bf16 convert of adjacency ----------------
__global__ __launch_bounds__(256) void cvt_bf16(const float* __restrict__ a,
                                                u16* __restrict__ o) {
  long i = ((long)blockIdx.x * 256 + threadIdx.x) * 8;
  if (i >= 100000000L) return;
  float4 x = *(const float4*)(a + i);
  float4 y = *(const float4*)(a + i + 4);
  u16x8 v;
  v[0]=f2bf(x.x); v[1]=f2bf(x.y); v[2]=f2bf(x.z); v[3]=f2bf(x.w);
  v[4]=f2bf(y.x); v[5]=f2bf(y.y); v[6]=f2bf(y.z); v[7]=f2bf(y.w);
  *(u16x8*)(o + i) = v;
}

// ---------------- transposed input embedding: Htin[c][m] = inputs[m][c] -----
__global__ __launch_bounds__(256) void prep_in(const float* __restrict__ in,
                                               u16* __restrict__ Htin) {
  int m = blockIdx.x * 256 + threadIdx.x;
  int c = blockIdx.y;
  if (m >= NN) return;
  Htin[(size_t)c * P + m] = f2bf(in[(size_t)m * 12 + c]);
}

// ---------------- combined weight builders ----------------
__global__ void build_w_enc(const float* __restrict__ W, const float* __restrict__ wemb,
    const float* __restrict__ bemb, const float* __restrict__ bsrc, int nout,
    u16* __restrict__ Wt, float* __restrict__ biasout) {
  int j = blockIdx.x, k = threadIdx.x;
  float v = 0.f;
  if (k < 64)        v = W[(64 + k) * nout + j] - W[(320 + k) * nout + j];
  else if (k < 128)  v = W[(192 + (k - 64)) * nout + j];
  else if (k < 192)  v = 2.f * W[(320 + (k - 128)) * nout + j];
  else if (k == 192) { float s = 0; for (int i = 0; i < 64; i++) s += wemb[i] * (W[i*nout+j] - W[(256+i)*nout+j]); v = s; }
  else if (k == 193) { float s = 0; for (int i = 0; i < 64; i++) s += wemb[i] * W[(128+i)*nout+j]; v = s; }
  else if (k == 194) { float s = 0; for (int i = 0; i < 64; i++) s += wemb[i] * W[(256+i)*nout+j]; v = 2.f * s; }
  Wt[j * 256 + k] = f2bf(v);
  if (k == 195) {
    float bb = bsrc[j];
    for (int i = 0; i < 64; i++) bb += bemb[i] * (W[i*nout+j] + W[(128+i)*nout+j] + W[(256+i)*nout+j]);
    biasout[j] = bb;
  }
}

__global__ void build_w_dec(const float* __restrict__ W, int nout, u16* __restrict__ Wt) {
  int j = blockIdx.x, k = threadIdx.x;
  float v = 0.f;
  if (k < 64)        v = W[(1 + k) * nout + j] - W[(131 + k) * nout + j];
  else if (k < 128)  v = W[(66 + (k - 64)) * nout + j];
  else if (k < 192)  v = 2.f * W[(131 + (k - 128)) * nout + j];
  else if (k == 192) v = W[0 * nout + j] - W[130 * nout + j];
  else if (k == 193) v = W[65 * nout + j];
  else if (k == 194) v = 2.f * W[130 * nout + j];
  Wt[j * 256 + k] = f2bf(v);
}

// ---------------- heavy pass: PT[s][c][m] = partial of (A @ Ht^T)^T ---------
// LDS tiles XOR-swizzled: LDS slot s of row r holds global k-slot (s ^ (r&7)).
// global_load_lds writes linearly, so the swizzle is applied on the GLOBAL
// source address at stage time and on the ds_read address at compute time;
// the two XORs cancel per lane, so MFMA operands are identical to unswizzled.
template <int NT>
__global__ __launch_bounds__(256) void gemm_bt_t(
    const u16* __restrict__ A, const u16* __restrict__ Ht,
    u16* __restrict__ PT) {
  __shared__ u16 Al[2][128 * 64];
  __shared__ u16 Bl[2][NT * 16 * 64];
  int tid = threadIdx.x;
  int wave = tid >> 6, lane = tid & 63, ml = lane & 15, q = lane >> 4;
  int row0 = blockIdx.x * 128;
  int kb = blockIdx.y * KSPLIT;
  int ke = (blockIdx.y == SPLITS - 1) ? KPAD : kb + KSPLIT;
  int nch = (ke - kb) >> 6;
  f32x4 acc[2][NT] = {};
  int r8 = tid >> 3, c8 = tid & 7;
  int csw = c8 ^ (r8 & 7);   // pre-swizzled k-slot for staging

  auto stageA = [&](int buf, int k0) {
    int kch = k0 + csw * 8;
    kch = kch > 9992 ? 9992 : kch;  // clamp; pairs against zero B slots
#pragma unroll
    for (int is = 0; is < 4; is++) {
      int row = row0 + is * 32 + r8;
      row = row > 9999 ? 9999 : row;
      load_lds16(A + (size_t)row * NN + kch,
                 (u16*)&Al[buf][0] + is * 2048 + wave * 512);
    }
  };
  auto stageB = [&](int buf, int k0) {
    int kk = k0 + csw * 8;  // Ht zero-padded to P past NN: no clamp needed
    if constexpr (NT >= 4) {
#pragma unroll
      for (int is = 0; is < 2; is++)
        load_lds16(Ht + (size_t)(is * 32 + r8) * P + kk,
                   (u16*)&Bl[buf][0] + is * 2048 + wave * 512);
    }
    if constexpr (NT == 5) {
      if (wave < 2)  // rows 64..79, waves 0-1 only
        load_lds16(Ht + (size_t)(64 + r8) * P + kk,
                   (u16*)&Bl[buf][0] + 4096 + wave * 512);
    }
    if constexpr (NT == 1) {
      if (wave < 2)  // rows 0..15, waves 0-1 only
        load_lds16(Ht + (size_t)r8 * P + kk,
                   (u16*)&Bl[buf][0] + wave * 512);
    }
  };

  stageA(0, kb);
  stageB(0, kb);
  for (int c = 0; c < nch; c++) {
    int buf = c & 1;
    if (c + 1 < nch) {
      stageA(buf ^ 1, kb + (c + 1) * 64);
      stageB(buf ^ 1, kb + (c + 1) * 64);
      __builtin_amdgcn_sched_barrier(0);
      // wait until only the just-issued loads are outstanding (counted, not 0)
      if constexpr (NT == 5) {
        if (wave < 2) asm volatile("s_waitcnt vmcnt(7)" ::: "memory");
        else          asm volatile("s_waitcnt vmcnt(6)" ::: "memory");
      } else if constexpr (NT == 4) {
        asm volatile("s_waitcnt vmcnt(6)" ::: "memory");
      } else {
        if (wave < 2) asm volatile("s_waitcnt vmcnt(5)" ::: "memory");
        else          asm volatile("s_waitcnt vmcnt(4)" ::: "memory");
      }
    } else {
      asm volatile("s_waitcnt vmcnt(0)" ::: "memory");
    }
    __builtin_amdgcn_sched_barrier(0);
    __builtin_amdgcn_s_barrier();       // publish buf
    __builtin_amdgcn_sched_barrier(0);
#pragma unroll
    for (int kh = 0; kh < 2; kh++) {
      int s = ((kh * 4 + q) ^ (ml & 7)) * 8;  // swizzled read slot
      short8 a0 = *(const short8*)(&Al[buf][0] + (wave * 32 + ml) * 64 + s);
      short8 a1 = *(const short8*)(&Al[buf][0] + (wave * 32 + 16 + ml) * 64 + s);
#pragma unroll
      for (int nt = 0; nt < NT; nt++) {
        short8 b = *(const short8*)(&Bl[buf][0] + (nt * 16 + ml) * 64 + s);
        acc[0][nt] = __builtin_amdgcn_mfma_f32_16x16x32_bf16(a0, b, acc[0][nt], 0, 0, 0);
        acc[1][nt] = __builtin_amdgcn_mfma_f32_16x16x32_bf16(a1, b, acc[1][nt], 0, 0, 0);
      }
    }
    __builtin_amdgcn_sched_barrier(0);
    __builtin_amdgcn_s_barrier();       // all waves done reading buf
    __builtin_amdgcn_sched_barrier(0);
  }
  u16* Pp = PT + (size_t)blockIdx.y * PLANE;
#pragma unroll
  for (int mt = 0; mt < 2; mt++)
#pragma unroll
    for (int nt = 0; nt < NT; nt++) {
      int j = nt * 16 + ml;
      int m = row0 + wave * 32 + mt * 16 + q * 4;
      u16x4 pk;
#pragma unroll
      for (int i = 0; i < 4; i++) pk[i] = f2bf(acc[mt][nt][i]);
      *(u16x4*)(Pp + (size_t)j * P + m) = pk;
    }
}

// ---------------- split reducer: T[c][m] = sum_s PT[s][c][m], zero m>=10000 -
__global__ __launch_bounds__(256) void red(const u16* __restrict__ PT,
                                           int ncols, u16* __restrict__ T) {
  int nch = ncols * 1264;  // P/8 chunks per col
  for (int cid = blockIdx.x * 256 + threadIdx.x; cid < nch; cid += gridDim.x * 256) {
    int c = cid / 1264;
    int mb8 = (cid - c * 1264) * 8;
    size_t base = (size_t)c * P + mb8;
    float a[8] = {};
#pragma unroll
    for (int s = 0; s < SPLITS; s++) {
      u16x8 v = *(const u16x8*)(PT + (size_t)s * PLANE + base);
#pragma unroll
      for (int i = 0; i < 8; i++) a[i] += bf2f(v[i]);
    }
    u16x8 o;
#pragma unroll
    for (int i = 0; i < 8; i++) o[i] = (mb8 >= NN) ? (u16)0 : f2bf(a[i]);
    *(u16x8*)(T + base) = o;
  }
}

// ---------------- fused cell projection (K=256) + GRU epilogue ----------------
// Same XOR swizzle on Al/Wl tiles (reads + all three staging paths).
__global__ __launch_bounds__(256) void cellmm(
    const u16* __restrict__ src0row,              // [m][64] bf16
    const u16* __restrict__ T1, const u16* __restrict__ T2,  // [c][P] bf16
    const u16* __restrict__ sc0, const u16* __restrict__ sc1,
    const u16* __restrict__ sc2,                  // bf16, unit m stride
    u16* __restrict__ sdec0, u16* __restrict__ sdec1,  // optional saves
    const u16* __restrict__ Wt, const float* __restrict__ bias,
    int ntiles, int mode,
    const float* __restrict__ hx,                 // fp32 [m][64]
    float* __restrict__ ubuf,                     // fp32 [m][64]
    float* __restrict__ hxout,                    // mode1 fp32 out
    u16* __restrict__ rowout,                     // bf16 [m][64]
    u16* __restrict__ htout) {                    // bf16 [j][P]
  __shared__ u16 Al[128 * 64];
  __shared__ u16 Wl[128 * 64];
  int tid = threadIdx.x;
  int wave = tid >> 6, lane = tid & 63, ml = lane & 15, q = lane >> 4;
  int m0 = blockIdx.x * 128;
  int r8 = tid >> 3, c8 = tid & 7;
  int csw = c8 ^ (r8 & 7);
  f32x4 acc[2][8] = {};
  for (int kc = 0; kc < 4; kc++) {
    if (kc == 0) {
#pragma unroll
      for (int is = 0; is < 4; is++) {
        int row = m0 + is * 32 + r8;
        load_lds16(src0row + (size_t)row * 64 + csw * 8,
                   (u16*)Al + is * 2048 + wave * 512);
      }
    } else if (kc < 3) {
      const u16* Ts = (kc == 1) ? T1 : T2;
      int c = tid >> 2;
      int mo = (tid & 3) * 32;
      const u16* sp = Ts + (size_t)c * P + m0 + mo;
      u16x8 v0 = *(const u16x8*)(sp);
      u16x8 v1 = *(const u16x8*)(sp + 8);
      u16x8 v2 = *(const u16x8*)(sp + 16);
      u16x8 v3 = *(const u16x8*)(sp + 24);
#pragma unroll
      for (int i = 0; i < 8; i++) {
        int cs = c ^ (i << 3);  // rows mo+i+{0,8,16,24} are all ≡ i (mod 8)
        Al[(mo + i) * 64 + cs]      = v0[i];
        Al[(mo + 8 + i) * 64 + cs]  = v1[i];
        Al[(mo + 16 + i) * 64 + cs] = v2[i];
        Al[(mo + 24 + i) * 64 + cs] = v3[i];
      }
    } else {
      int r = tid >> 1, half = tid & 1;
      int m = m0 + r;
      int x = (r & 7) << 3;
      u16* rowp = Al + r * 64;
      if (half == 0) {
        u16 a = sc0[m], b = sc1[m], cc = sc2[m];
        rowp[0 ^ x] = a; rowp[1 ^ x] = b; rowp[2 ^ x] = cc;
#pragma unroll
        for (int jj = 3; jj < 32; jj++) rowp[jj ^ x] = 0;
        if (sdec0) { sdec0[m] = b; sdec1[m] = cc; }
      } else {
#pragma unroll
        for (int jj = 32; jj < 64; jj++) rowp[jj ^ x] = 0;
      }
    }
    int wiss = ntiles >> 1;
    for (int is = 0; is < wiss; is++) {
      int jr = is * 32 + r8;
      load_lds16(Wt + (size_t)jr * 256 + kc * 64 + csw * 8,
                 (u16*)Wl + is * 2048 + wave * 512);
    }
    __syncthreads();
#pragma unroll
    for (int kh = 0; kh < 2; kh++) {
      int s = ((kh * 4 + q) ^ (ml & 7)) * 8;
      short8 a0 = *(const short8*)(Al + (wave * 32 + ml) * 64 + s);
      short8 a1 = *(const short8*)(Al + (wave * 32 + 16 + ml) * 64 + s);
#pragma unroll
      for (int nt = 0; nt < 8; nt++) {
        if (nt < ntiles) {
          short8 b = *(const short8*)(Wl + (nt * 16 + ml) * 64 + s);
          acc[0][nt] = __builtin_amdgcn_mfma_f32_16x16x32_bf16(a0, b, acc[0][nt], 0, 0, 0);
          acc[1][nt] = __builtin_amdgcn_mfma_f32_16x16x32_bf16(a1, b, acc[1][nt], 0, 0, 0);
        }
      }
    }
    __syncthreads();
  }
#pragma unroll
  for (int mt = 0; mt < 2; mt++)
#pragma unroll
    for (int nt = 0; nt < 8; nt++)
      if (nt < ntiles) {
        int j = nt * 16 + ml;
        int mb = m0 + wave * 32 + mt * 16 + q * 4;
        u16x4 pk;
        if (mode == 0) {
          if (j < 64) {
#pragma unroll
            for (int i = 0; i < 4; i++) {
              int m = mb + i;
              float g = acc[mt][nt][i] + bias[j];
              float s = 1.f / (1.f + __expf(-g));
              float rv = s * hx[(size_t)m * 64 + j];
              rowout[(size_t)m * 64 + j] = f2bf(rv);
              pk[i] = f2bf(rv);
            }
            if (mb < NN) *(u16x4*)(htout + (size_t)j * P + mb) = pk;
          } else {
#pragma unroll
            for (int i = 0; i < 4; i++) {
              int m = mb + i;
              float g = acc[mt][nt][i] + bias[j];
              ubuf[(size_t)m * 64 + (j - 64)] = 1.f / (1.f + __expf(-g));
            }
          }
        } else {
#pragma unroll
          for (int i = 0; i < 4; i++) {
            int m = mb + i;
            float g = acc[mt][nt][i] + bias[j];
            float cc = 1.f - 2.f / (__expf(2.f * g) + 1.f);
            float uu = ubuf[(size_t)m * 64 + j];
            float hv = hx[(size_t)m * 64 + j];
            float hn = uu * hv + (1.f - uu) * cc;
            hxout[(size_t)m * 64 + j] = hn;
            rowout[(size_t)m * 64 + j] = f2bf(hn);
            pk[i] = f2bf(hn);
          }
          if (mb < NN) *(u16x4*)(htout + (size_t)j * P + mb) = pk;
        }
      }
}

// ---------------- decoder prediction ----------------
__global__ __launch_bounds__(256) void pred_k(const float* __restrict__ hx,
    const float* __restrict__ Wp, const float* __restrict__ bp,
    float* __restrict__ out, u16* __restrict__ xrow, u16* __restrict__ Ht1,
    int t) {
  int m = blockIdx.x * 256 + threadIdx.x;
  if (m >= P) return;
  const float* h = hx + (size_t)m * 64;
  float s = bp[0];
#pragma unroll
  for (int j = 0; j < 64; j += 4) {
    float4 f = *(const float4*)(h + j);
    s += f.x * Wp[j] + f.y * Wp[j + 1] + f.z * Wp[j + 2] + f.w * Wp[j + 3];
  }
  u16 sb = f2bf(s);
  xrow[m] = sb;
  if (m < NN) {
    Ht1[(size_t)64 * P + m] = sb;
    out[(size_t)m * 12 + t] = s;
  }
}

extern "C" void kernel_launch(void* const* d_in, const int* in_sizes, int n_in,
                              void* d_out, int out_size, void* d_ws, size_t ws_size,
                              hipStream_t stream) {
  const float* inputs = (const float*)d_in[0];
  const float* adj    = (const float*)d_in[2];
  const float* W_emb  = (const float*)d_in[3];
  const float* b_emb  = (const float*)d_in[4];
  const float* Wg_e   = (const float*)d_in[5];
  const float* bg_e   = (const float*)d_in[6];
  const float* Wc_e   = (const float*)d_in[7];
  const float* bc_e   = (const float*)d_in[8];
  const float* Wg_d   = (const float*)d_in[9];
  const float* bg_d   = (const float*)d_in[10];
  const float* Wc_d   = (const float*)d_in[11];
  const float* bc_d   = (const float*)d_in[12];
  const float* W_pred = (const float*)d_in[13];
  const float* b_pred = (const float*)d_in[14];
  float* out = (float*)d_out;
  char* ws = (char*)d_ws;

  size_t off = 0;
  auto alloc = [&](size_t bytes) -> void* {
    void* p = ws + off;
    off += (bytes + 511) & ~(size_t)511;
    return p;
  };
  u16*   A16    = (u16*)  alloc(200000000ULL);
  u16*   PT1    = (u16*)  alloc((size_t)SPLITS * PLANE * 2);
  u16*   PT2    = (u16*)  alloc((size_t)SPLITS * PLANE * 2);
  u16*   Ht1    = (u16*)  alloc((size_t)80 * P * 2);
  u16*   T1     = (u16*)  alloc((size_t)80 * P * 2);
  u16*   T2     = (u16*)  alloc((size_t)80 * P * 2);
  u16*   HtR    = (u16*)  alloc((size_t)64 * P * 2);
  u16*   Htin   = (u16*)  alloc((size_t)16 * P * 2);
  u16*   Ts1    = (u16*)  alloc((size_t)16 * P * 2);
  u16*   Ts2    = (u16*)  alloc((size_t)16 * P * 2);
  float* hx     = (float*)alloc((size_t)P * 64 * 4);
  float* ub     = (float*)alloc((size_t)P * 64 * 4);
  u16*   hxrow  = (u16*)  alloc((size_t)P * 64 * 2);
  u16*   rhrow  = (u16*)  alloc((size_t)P * 64 * 2);
  u16*   xrow   = (u16*)  alloc((size_t)P * 2);
  u16*   sdec   = (u16*)  alloc((size_t)2 * P * 2);
  u16*   Wt_eg  = (u16*)  alloc(128 * 256 * 2);
  u16*   Wt_ec  = (u16*)  alloc(64 * 256 * 2);
  u16*   Wt_dg  = (u16*)  alloc(128 * 256 * 2);
  u16*   Wt_dc  = (u16*)  alloc(64 * 256 * 2);
  float* bias_eg= (float*)alloc(128 * 4);
  float* bias_ec= (float*)alloc(64 * 4);
  if (off > ws_size) return;  // ws too small (absmax ~0.129 signal)

  hipMemsetAsync(Ht1, 0, (size_t)80 * P * 2, stream);
  hipMemsetAsync(HtR, 0, (size_t)64 * P * 2, stream);
  hipMemsetAsync(Htin, 0, (size_t)16 * P * 2, stream);
  hipMemsetAsync(hx, 0, (size_t)P * 64 * 4, stream);
  hipMemsetAsync(hxrow, 0, (size_t)P * 64 * 2, stream);
  hipMemsetAsync(xrow, 0, (size_t)P * 2, stream);

  cvt_bf16<<<48829, 256, 0, stream>>>(adj, A16);
  prep_in<<<dim3(40, 12), 256, 0, stream>>>(inputs, Htin);
  build_w_enc<<<128, 256, 0, stream>>>(Wg_e, W_emb, b_emb, bg_e, 128, Wt_eg, bias_eg);
  build_w_enc<<<64, 256, 0, stream>>>(Wc_e, W_emb, b_emb, bc_e, 64, Wt_ec, bias_ec);
  build_w_dec<<<128, 256, 0, stream>>>(Wg_d, 128, Wt_dg);
  build_w_dec<<<64, 256, 0, stream>>>(Wc_d, 64, Wt_dc);

  dim3 ggrid(79, SPLITS);
  // scalar-diffusion prepass: Ts1 = (A@inputs)^T, Ts2 = (A@A@inputs)^T
  gemm_bt_t<1><<<ggrid, 256, 0, stream>>>(A16, Htin, PT1);
  red<<<256, 256, 0, stream>>>(PT1, 16, Ts1);
  gemm_bt_t<1><<<ggrid, 256, 0, stream>>>(A16, Ts1, PT2);
  red<<<256, 256, 0, stream>>>(PT2, 16, Ts2);

  for (int t = 0; t < 12; t++) {
    gemm_bt_t<4><<<ggrid, 256, 0, stream>>>(A16, Ht1, PT1);
    red<<<256, 256, 0, stream>>>(PT1, 64, T1);
    gemm_bt_t<4><<<ggrid, 256, 0, stream>>>(A16, T1, PT2);
    red<<<256, 256, 0, stream>>>(PT2, 64, T2);
    cellmm<<<79, 256, 0, stream>>>(hxrow, T1, T2,
        Htin + (size_t)t * P, Ts1 + (size_t)t * P, Ts2 + (size_t)t * P,
        (u16*)nullptr, (u16*)nullptr, Wt_eg, bias_eg, 8, 0,
        hx, ub, (float*)nullptr, rhrow, HtR);
    gemm_bt_t<4><<<ggrid, 256, 0, stream>>>(A16, HtR, PT1);
    red<<<256, 256, 0, stream>>>(PT1, 64, T1);
    gemm_bt_t<4><<<ggrid, 256, 0, stream>>>(A16, T1, PT2);
    red<<<256, 256, 0, stream>>>(PT2, 64, T2);
    cellmm<<<79, 256, 0, stream>>>(rhrow, T1, T2,
        Htin + (size_t)t * P, Ts1 + (size_t)t * P, Ts2 + (size_t)t * P,
        (u16*)nullptr, (u16*)nullptr, Wt_ec, bias_ec, 4, 1,
        hx, ub, hx, hxrow, Ht1);
  }
  for (int t = 0; t < 12; t++) {
    gemm_bt_t<5><<<ggrid, 256, 0, stream>>>(A16, Ht1, PT1);
    red<<<256, 256, 0, stream>>>(PT1, 80, T1);
    gemm_bt_t<5><<<ggrid, 256, 0, stream>>>(A16, T1, PT2);
    red<<<256, 256, 0, stream>>>(PT2, 80, T2);
    cellmm<<<79, 256, 0, stream>>>(hxrow, T1, T2,
        xrow, T1 + (size_t)64 * P, T2 + (size_t)64 * P,
        sdec, sdec + P, Wt_dg, bg_d, 8, 0,
        hx, ub, (float*)nullptr, rhrow, HtR);
    gemm_bt_t<4><<<ggrid, 256, 0, stream>>>(A16, HtR, PT1);
    red<<<256, 256, 0, stream>>>(PT1, 64, T1);
    gemm_bt_t<4><<<ggrid, 256, 0, stream>>>(A16, T1, PT2);
    red<<<256, 256, 0, stream>>>(PT2, 64, T2);
    cellmm<<<79, 256, 0, stream>>>(rhrow, T1, T2,
        xrow, sdec, sdec + P,
        (u16*)nullptr, (u16*)nullptr, Wt_dc, bc_d, 4, 1,
        hx, ub, hx, hxrow, Ht1);
    pred_k<<<40, 256, 0, stream>>>(hx, W_pred, b_pred, out, xrow, Ht1, t);
  }
}

// Round 2
// 5712.962 us; speedup vs baseline: 1.2193x; 1.0997x over previous
//
#include <hip/hip_runtime.h>

// GTS forecasting (DCGRU enc-dec over dense 10000x10000 adjacency), gfx950.
// R4: A repacked once (pack_a, fused fp32->bf16) into exact per-(rowblock,
// k-chunk) staging order with the XOR swizzle pre-baked, so gemm_bt's A
// stream is fully linear (1KB-coalesced global_load_lds, contiguous 1.6MB
// per block k-slice) instead of scattered 128B granules at 20KB stride.
// LDS image is bit-identical to R3; compute loop untouched.

typedef unsigned short u16;
typedef __attribute__((ext_vector_type(8))) short short8;
typedef __attribute__((ext_vector_type(8))) unsigned short u16x8;
typedef __attribute__((ext_vector_type(4))) unsigned short u16x4;
typedef __attribute__((ext_vector_type(4))) float f32x4;

#define NN 10000
#define P 10112          // padded m pitch (79*128)
#define KPAD 10048       // 157*64 k-chunks
#define NCHUNK 157
#define SPLITS 13
#define KSPLIT 768       // 12 chunks per split; last split gets 13
#define PLANE 808960     // 80*P shorts per split plane

__device__ __forceinline__ u16 f2bf(float f) {
  unsigned u = __float_as_uint(f);
  unsigned r = (u + 0x7FFFu + ((u >> 16) & 1u)) >> 16;
  return (u16)r;
}
__device__ __forceinline__ float bf2f(u16 v) {
  return __uint_as_float((unsigned)v << 16);
}

__device__ __forceinline__ void load_lds16(const void* g, void* l) {
  __builtin_amdgcn_global_load_lds(
      (__attribute__((address_space(1))) void*)(void*)g,
      (__attribute__((address_space(3))) void*)l, 16, 0, 0);
}

// ---------------- A packer: fp32 adj -> bf16 tile-staging layout ----------
// A2[((bx*157 + g) * 8192) + is*2048 + w*512 + lane*8 + e] =
//   bf16( adj[bx*128 + is*32 + 8w + (lane>>3)][g*64 + ((lane&7)^((lane>>3)&7))*8 + e] )
// (zero when row>=NN or k>=NN). This makes gemm stageA's per-lane global
// address exactly linear while reproducing R3's swizzled LDS image.
__global__ __launch_bounds__(256) void pack_a(const float* __restrict__ a,
                                              u16* __restrict__ A2) {
  int bx = blockIdx.x, g = blockIdx.y;
  size_t tb = ((size_t)bx * NCHUNK + g) << 13;
#pragma unroll
  for (int q = 0; q < 4; q++) {
    int s = q * 256 + threadIdx.x;
    int is = s >> 8, w = (s >> 6) & 3, lane = s & 63;
    int row = bx * 128 + is * 32 + 8 * w + (lane >> 3);
    int k = g * 64 + (((lane & 7) ^ ((lane >> 3) & 7)) << 3);
    u16x8 v = {};
    if (row < NN && k < NN) {
      float4 x = *(const float4*)(a + (size_t)row * NN + k);
      float4 y = *(const float4*)(a + (size_t)row * NN + k + 4);
      v[0]=f2bf(x.x); v[1]=f2bf(x.y); v[2]=f2bf(x.z); v[3]=f2bf(x.w);
      v[4]=f2bf(y.x); v[5]=f2bf(y.y); v[6]=f2bf(y.z); v[7]=f2bf(y.w);
    }
    *(u16x8*)(A2 + tb + (size_t)s * 8) = v;
  }
}

// ---------------- transposed input embedding: Htin[c][m] = inputs[m][c] -----
__global__ __launch_bounds__(256) void prep_in(const float* __restrict__ in,
                                               u16* __restrict__ Htin) {
  int m = blockIdx.x * 256 + threadIdx.x;
  int c = blockIdx.y;
  if (m >= NN) return;
  Htin[(size_t)c * P + m] = f2bf(in[(size_t)m * 12 + c]);
}

// ---------------- combined weight builders ----------------
__global__ void build_w_enc(const float* __restrict__ W, const float* __restrict__ wemb,
    const float* __restrict__ bemb, const float* __restrict__ bsrc, int nout,
    u16* __restrict__ Wt, float* __restrict__ biasout) {
  int j = blockIdx.x, k = threadIdx.x;
  float v = 0.f;
  if (k < 64)        v = W[(64 + k) * nout + j] - W[(320 + k) * nout + j];
  else if (k < 128)  v = W[(192 + (k - 64)) * nout + j];
  else if (k < 192)  v = 2.f * W[(320 + (k - 128)) * nout + j];
  else if (k == 192) { float s = 0; for (int i = 0; i < 64; i++) s += wemb[i] * (W[i*nout+j] - W[(256+i)*nout+j]); v = s; }
  else if (k == 193) { float s = 0; for (int i = 0; i < 64; i++) s += wemb[i] * W[(128+i)*nout+j]; v = s; }
  else if (k == 194) { float s = 0; for (int i = 0; i < 64; i++) s += wemb[i] * W[(256+i)*nout+j]; v = 2.f * s; }
  Wt[j * 256 + k] = f2bf(v);
  if (k == 195) {
    float bb = bsrc[j];
    for (int i = 0; i < 64; i++) bb += bemb[i] * (W[i*nout+j] + W[(128+i)*nout+j] + W[(256+i)*nout+j]);
    biasout[j] = bb;
  }
}

__global__ void build_w_dec(const float* __restrict__ W, int nout, u16* __restrict__ Wt) {
  int j = blockIdx.x, k = threadIdx.x;
  float v = 0.f;
  if (k < 64)        v = W[(1 + k) * nout + j] - W[(131 + k) * nout + j];
  else if (k < 128)  v = W[(66 + (k - 64)) * nout + j];
  else if (k < 192)  v = 2.f * W[(131 + (k - 128)) * nout + j];
  else if (k == 192) v = W[0 * nout + j] - W[130 * nout + j];
  else if (k == 193) v = W[65 * nout + j];
  else if (k == 194) v = 2.f * W[130 * nout + j];
  Wt[j * 256 + k] = f2bf(v);
}

// ---------------- heavy pass: PT[s][c][m] = partial of (A @ Ht^T)^T ---------
// A comes pre-packed (pack_a): stageA per-lane addresses are linear.
// B tiles XOR-swizzled from strided Ht (L2-resident, stride-gather fine).
template <int NT>
__global__ __launch_bounds__(256) void gemm_bt_t(
    const u16* __restrict__ A2, const u16* __restrict__ Ht,
    u16* __restrict__ PT) {
  __shared__ u16 Al[2][128 * 64];
  __shared__ u16 Bl[2][NT * 16 * 64];
  int tid = threadIdx.x;
  int wave = tid >> 6, lane = tid & 63, ml = lane & 15, q = lane >> 4;
  int row0 = blockIdx.x * 128;
  int g0 = blockIdx.y * 12;
  int nch = (blockIdx.y == SPLITS - 1) ? 13 : 12;
  f32x4 acc[2][NT] = {};
  int r8 = tid >> 3, c8 = tid & 7;
  int csw = c8 ^ (r8 & 7);   // pre-swizzled k-slot for B staging

  const u16* Abase = A2 + (((size_t)blockIdx.x * NCHUNK + g0) << 13)
                        + wave * 512 + (size_t)lane * 8;

  auto stageA = [&](int buf, int c) {
    const u16* src = Abase + ((size_t)c << 13);
#pragma unroll
    for (int is = 0; is < 4; is++)
      load_lds16(src + is * 2048, (u16*)&Al[buf][0] + is * 2048 + wave * 512);
  };
  auto stageB = [&](int buf, int c) {
    int kk = (g0 + c) * 64 + csw * 8;  // Ht zero-padded past NN
    if constexpr (NT >= 4) {
#pragma unroll
      for (int is = 0; is < 2; is++)
        load_lds16(Ht + (size_t)(is * 32 + r8) * P + kk,
                   (u16*)&Bl[buf][0] + is * 2048 + wave * 512);
    }
    if constexpr (NT == 5) {
      if (wave < 2)  // rows 64..79, waves 0-1 only
        load_lds16(Ht + (size_t)(64 + r8) * P + kk,
                   (u16*)&Bl[buf][0] + 4096 + wave * 512);
    }
    if constexpr (NT == 1) {
      if (wave < 2)  // rows 0..15, waves 0-1 only
        load_lds16(Ht + (size_t)r8 * P + kk,
                   (u16*)&Bl[buf][0] + wave * 512);
    }
  };

  stageA(0, 0);
  stageB(0, 0);
  for (int c = 0; c < nch; c++) {
    int buf = c & 1;
    if (c + 1 < nch) {
      stageA(buf ^ 1, c + 1);
      stageB(buf ^ 1, c + 1);
      __builtin_amdgcn_sched_barrier(0);
      // wait until only the just-issued loads are outstanding (counted, not 0)
      if constexpr (NT == 5) {
        if (wave < 2) asm volatile("s_waitcnt vmcnt(7)" ::: "memory");
        else          asm volatile("s_waitcnt vmcnt(6)" ::: "memory");
      } else if constexpr (NT == 4) {
        asm volatile("s_waitcnt vmcnt(6)" ::: "memory");
      } else {
        if (wave < 2) asm volatile("s_waitcnt vmcnt(5)" ::: "memory");
        else          asm volatile("s_waitcnt vmcnt(4)" ::: "memory");
      }
    } else {
      asm volatile("s_waitcnt vmcnt(0)" ::: "memory");
    }
    __builtin_amdgcn_sched_barrier(0);
    __builtin_amdgcn_s_barrier();       // publish buf
    __builtin_amdgcn_sched_barrier(0);
#pragma unroll
    for (int kh = 0; kh < 2; kh++) {
      int s = ((kh * 4 + q) ^ (ml & 7)) * 8;  // swizzled read slot
      short8 a0 = *(const short8*)(&Al[buf][0] + (wave * 32 + ml) * 64 + s);
      short8 a1 = *(const short8*)(&Al[buf][0] + (wave * 32 + 16 + ml) * 64 + s);
#pragma unroll
      for (int nt = 0; nt < NT; nt++) {
        short8 b = *(const short8*)(&Bl[buf][0] + (nt * 16 + ml) * 64 + s);
        acc[0][nt] = __builtin_amdgcn_mfma_f32_16x16x32_bf16(a0, b, acc[0][nt], 0, 0, 0);
        acc[1][nt] = __builtin_amdgcn_mfma_f32_16x16x32_bf16(a1, b, acc[1][nt], 0, 0, 0);
      }
    }
    __builtin_amdgcn_sched_barrier(0);
    __builtin_amdgcn_s_barrier();       // all waves done reading buf
    __builtin_amdgcn_sched_barrier(0);
  }
  u16* Pp = PT + (size_t)blockIdx.y * PLANE;
#pragma unroll
  for (int mt = 0; mt < 2; mt++)
#pragma unroll
    for (int nt = 0; nt < NT; nt++) {
      int j = nt * 16 + ml;
      int m = row0 + wave * 32 + mt * 16 + q * 4;
      u16x4 pk;
#pragma unroll
      for (int i = 0; i < 4; i++) pk[i] = f2bf(acc[mt][nt][i]);
      *(u16x4*)(Pp + (size_t)j * P + m) = pk;
    }
}

// ---------------- split reducer: T[c][m] = sum_s PT[s][c][m], zero m>=10000 -
__global__ __launch_bounds__(256) void red(const u16* __restrict__ PT,
                                           int ncols, u16* __restrict__ T) {
  int nch = ncols * 1264;  // P/8 chunks per col
  for (int cid = blockIdx.x * 256 + threadIdx.x; cid < nch; cid += gridDim.x * 256) {
    int c = cid / 1264;
    int mb8 = (cid - c * 1264) * 8;
    size_t base = (size_t)c * P + mb8;
    float a[8] = {};
#pragma unroll
    for (int s = 0; s < SPLITS; s++) {
      u16x8 v = *(const u16x8*)(PT + (size_t)s * PLANE + base);
#pragma unroll
      for (int i = 0; i < 8; i++) a[i] += bf2f(v[i]);
    }
    u16x8 o;
#pragma unroll
    for (int i = 0; i < 8; i++) o[i] = (mb8 >= NN) ? (u16)0 : f2bf(a[i]);
    *(u16x8*)(T + base) = o;
  }
}

// ---------------- fused cell projection (K=256) + GRU epilogue ----------------
// Same XOR swizzle on Al/Wl tiles (reads + all three staging paths).
__global__ __launch_bounds__(256) void cellmm(
    const u16* __restrict__ src0row,              // [m][64] bf16
    const u16* __restrict__ T1, const u16* __restrict__ T2,  // [c][P] bf16
    const u16* __restrict__ sc0, const u16* __restrict__ sc1,
    const u16* __restrict__ sc2,                  // bf16, unit m stride
    u16* __restrict__ sdec0, u16* __restrict__ sdec1,  // optional saves
    const u16* __restrict__ Wt, const float* __restrict__ bias,
    int ntiles, int mode,
    const float* __restrict__ hx,                 // fp32 [m][64]
    float* __restrict__ ubuf,                     // fp32 [m][64]
    float* __restrict__ hxout,                    // mode1 fp32 out
    u16* __restrict__ rowout,                     // bf16 [m][64]
    u16* __restrict__ htout) {                    // bf16 [j][P]
  __shared__ u16 Al[128 * 64];
  __shared__ u16 Wl[128 * 64];
  int tid = threadIdx.x;
  int wave = tid >> 6, lane = tid & 63, ml = lane & 15, q = lane >> 4;
  int m0 = blockIdx.x * 128;
  int r8 = tid >> 3, c8 = tid & 7;
  int csw = c8 ^ (r8 & 7);
  f32x4 acc[2][8] = {};
  for (int kc = 0; kc < 4; kc++) {
    if (kc == 0) {
#pragma unroll
      for (int is = 0; is < 4; is++) {
        int row = m0 + is * 32 + r8;
        load_lds16(src0row + (size_t)row * 64 + csw * 8,
                   (u16*)Al + is * 2048 + wave * 512);
      }
    } else if (kc < 3) {
      const u16* Ts = (kc == 1) ? T1 : T2;
      int c = tid >> 2;
      int mo = (tid & 3) * 32;
      const u16* sp = Ts + (size_t)c * P + m0 + mo;
      u16x8 v0 = *(const u16x8*)(sp);
      u16x8 v1 = *(const u16x8*)(sp + 8);
      u16x8 v2 = *(const u16x8*)(sp + 16);
      u16x8 v3 = *(const u16x8*)(sp + 24);
#pragma unroll
      for (int i = 0; i < 8; i++) {
        int cs = c ^ (i << 3);  // rows mo+i+{0,8,16,24} are all ≡ i (mod 8)
        Al[(mo + i) * 64 + cs]      = v0[i];
        Al[(mo + 8 + i) * 64 + cs]  = v1[i];
        Al[(mo + 16 + i) * 64 + cs] = v2[i];
        Al[(mo + 24 + i) * 64 + cs] = v3[i];
      }
    } else {
      int r = tid >> 1, half = tid & 1;
      int m = m0 + r;
      int x = (r & 7) << 3;
      u16* rowp = Al + r * 64;
      if (half == 0) {
        u16 a = sc0[m], b = sc1[m], cc = sc2[m];
        rowp[0 ^ x] = a; rowp[1 ^ x] = b; rowp[2 ^ x] = cc;
#pragma unroll
        for (int jj = 3; jj < 32; jj++) rowp[jj ^ x] = 0;
        if (sdec0) { sdec0[m] = b; sdec1[m] = cc; }
      } else {
#pragma unroll
        for (int jj = 32; jj < 64; jj++) rowp[jj ^ x] = 0;
      }
    }
    int wiss = ntiles >> 1;
    for (int is = 0; is < wiss; is++) {
      int jr = is * 32 + r8;
      load_lds16(Wt + (size_t)jr * 256 + kc * 64 + csw * 8,
                 (u16*)Wl + is * 2048 + wave * 512);
    }
    __syncthreads();
#pragma unroll
    for (int kh = 0; kh < 2; kh++) {
      int s = ((kh * 4 + q) ^ (ml & 7)) * 8;
      short8 a0 = *(const short8*)(Al + (wave * 32 + ml) * 64 + s);
      short8 a1 = *(const short8*)(Al + (wave * 32 + 16 + ml) * 64 + s);
#pragma unroll
      for (int nt = 0; nt < 8; nt++) {
        if (nt < ntiles) {
          short8 b = *(const short8*)(Wl + (nt * 16 + ml) * 64 + s);
          acc[0][nt] = __builtin_amdgcn_mfma_f32_16x16x32_bf16(a0, b, acc[0][nt], 0, 0, 0);
          acc[1][nt] = __builtin_amdgcn_mfma_f32_16x16x32_bf16(a1, b, acc[1][nt], 0, 0, 0);
        }
      }
    }
    __syncthreads();
  }
#pragma unroll
  for (int mt = 0; mt < 2; mt++)
#pragma unroll
    for (int nt = 0; nt < 8; nt++)
      if (nt < ntiles) {
        int j = nt * 16 + ml;
        int mb = m0 + wave * 32 + mt * 16 + q * 4;
        u16x4 pk;
        if (mode == 0) {
          if (j < 64) {
#pragma unroll
            for (int i = 0; i < 4; i++) {
              int m = mb + i;
              float g = acc[mt][nt][i] + bias[j];
              float s = 1.f / (1.f + __expf(-g));
              float rv = s * hx[(size_t)m * 64 + j];
              rowout[(size_t)m * 64 + j] = f2bf(rv);
              pk[i] = f2bf(rv);
            }
            if (mb < NN) *(u16x4*)(htout + (size_t)j * P + mb) = pk;
          } else {
#pragma unroll
            for (int i = 0; i < 4; i++) {
              int m = mb + i;
              float g = acc[mt][nt][i] + bias[j];
              ubuf[(size_t)m * 64 + (j - 64)] = 1.f / (1.f + __expf(-g));
            }
          }
        } else {
#pragma unroll
          for (int i = 0; i < 4; i++) {
            int m = mb + i;
            float g = acc[mt][nt][i] + bias[j];
            float cc = 1.f - 2.f / (__expf(2.f * g) + 1.f);
            float uu = ubuf[(size_t)m * 64 + j];
            float hv = hx[(size_t)m * 64 + j];
            float hn = uu * hv + (1.f - uu) * cc;
            hxout[(size_t)m * 64 + j] = hn;
            rowout[(size_t)m * 64 + j] = f2bf(hn);
            pk[i] = f2bf(hn);
          }
          if (mb < NN) *(u16x4*)(htout + (size_t)j * P + mb) = pk;
        }
      }
}

// ---------------- decoder prediction ----------------
__global__ __launch_bounds__(256) void pred_k(const float* __restrict__ hx,
    const float* __restrict__ Wp, const float* __restrict__ bp,
    float* __restrict__ out, u16* __restrict__ xrow, u16* __restrict__ Ht1,
    int t) {
  int m = blockIdx.x * 256 + threadIdx.x;
  if (m >= P) return;
  const float* h = hx + (size_t)m * 64;
  float s = bp[0];
#pragma unroll
  for (int j = 0; j < 64; j += 4) {
    float4 f = *(const float4*)(h + j);
    s += f.x * Wp[j] + f.y * Wp[j + 1] + f.z * Wp[j + 2] + f.w * Wp[j + 3];
  }
  u16 sb = f2bf(s);
  xrow[m] = sb;
  if (m < NN) {
    Ht1[(size_t)64 * P + m] = sb;
    out[(size_t)m * 12 + t] = s;
  }
}

extern "C" void kernel_launch(void* const* d_in, const int* in_sizes, int n_in,
                              void* d_out, int out_size, void* d_ws, size_t ws_size,
                              hipStream_t stream) {
  const float* inputs = (const float*)d_in[0];
  const float* adj    = (const float*)d_in[2];
  const float* W_emb  = (const float*)d_in[3];
  const float* b_emb  = (const float*)d_in[4];
  const float* Wg_e   = (const float*)d_in[5];
  const float* bg_e   = (const float*)d_in[6];
  const float* Wc_e   = (const float*)d_in[7];
  const float* bc_e   = (const float*)d_in[8];
  const float* Wg_d   = (const float*)d_in[9];
  const float* bg_d   = (const float*)d_in[10];
  const float* Wc_d   = (const float*)d_in[11];
  const float* bc_d   = (const float*)d_in[12];
  const float* W_pred = (const float*)d_in[13];
  const float* b_pred = (const float*)d_in[14];
  float* out = (float*)d_out;
  char* ws = (char*)d_ws;

  size_t off = 0;
  auto alloc = [&](size_t bytes) -> void* {
    void* p = ws + off;
    off += (bytes + 511) & ~(size_t)511;
    return p;
  };
  u16*   A2     = (u16*)  alloc((size_t)79 * NCHUNK * 8192 * 2);  // 203.2 MB
  u16*   PT1    = (u16*)  alloc((size_t)SPLITS * PLANE * 2);
  u16*   PT2    = (u16*)  alloc((size_t)SPLITS * PLANE * 2);
  u16*   Ht1    = (u16*)  alloc((size_t)80 * P * 2);
  u16*   T1     = (u16*)  alloc((size_t)80 * P * 2);
  u16*   T2     = (u16*)  alloc((size_t)80 * P * 2);
  u16*   HtR    = (u16*)  alloc((size_t)64 * P * 2);
  u16*   Htin   = (u16*)  alloc((size_t)16 * P * 2);
  u16*   Ts1    = (u16*)  alloc((size_t)16 * P * 2);
  u16*   Ts2    = (u16*)  alloc((size_t)16 * P * 2);
  float* hx     = (float*)alloc((size_t)P * 64 * 4);
  float* ub     = (float*)alloc((size_t)P * 64 * 4);
  u16*   hxrow  = (u16*)  alloc((size_t)P * 64 * 2);
  u16*   rhrow  = (u16*)  alloc((size_t)P * 64 * 2);
  u16*   xrow   = (u16*)  alloc((size_t)P * 2);
  u16*   sdec   = (u16*)  alloc((size_t)2 * P * 2);
  u16*   Wt_eg  = (u16*)  alloc(128 * 256 * 2);
  u16*   Wt_ec  = (u16*)  alloc(64 * 256 * 2);
  u16*   Wt_dg  = (u16*)  alloc(128 * 256 * 2);
  u16*   Wt_dc  = (u16*)  alloc(64 * 256 * 2);
  float* bias_eg= (float*)alloc(128 * 4);
  float* bias_ec= (float*)alloc(64 * 4);
  if (off > ws_size) return;  // ws too small (absmax ~0.129 signal)

  hipMemsetAsync(Ht1, 0, (size_t)80 * P * 2, stream);
  hipMemsetAsync(HtR, 0, (size_t)64 * P * 2, stream);
  hipMemsetAsync(Htin, 0, (size_t)16 * P * 2, stream);
  hipMemsetAsync(hx, 0, (size_t)P * 64 * 4, stream);
  hipMemsetAsync(hxrow, 0, (size_t)P * 64 * 2, stream);
  hipMemsetAsync(xrow, 0, (size_t)P * 2, stream);

  pack_a<<<dim3(79, NCHUNK), 256, 0, stream>>>(adj, A2);
  prep_in<<<dim3(40, 12), 256, 0, stream>>>(inputs, Htin);
  build_w_enc<<<128, 256, 0, stream>>>(Wg_e, W_emb, b_emb, bg_e, 128, Wt_eg, bias_eg);
  build_w_enc<<<64, 256, 0, stream>>>(Wc_e, W_emb, b_emb, bc_e, 64, Wt_ec, bias_ec);
  build_w_dec<<<128, 256, 0, stream>>>(Wg_d, 128, Wt_dg);
  build_w_dec<<<64, 256, 0, stream>>>(Wc_d, 64, Wt_dc);

  dim3 ggrid(79, SPLITS);
  // scalar-diffusion prepass: Ts1 = (A@inputs)^T, Ts2 = (A@A@inputs)^T
  gemm_bt_t<1><<<ggrid, 256, 0, stream>>>(A2, Htin, PT1);
  red<<<79, 256, 0, stream>>>(PT1, 16, Ts1);
  gemm_bt_t<1><<<ggrid, 256, 0, stream>>>(A2, Ts1, PT2);
  red<<<79, 256, 0, stream>>>(PT2, 16, Ts2);

  for (int t = 0; t < 12; t++) {
    gemm_bt_t<4><<<ggrid, 256, 0, stream>>>(A2, Ht1, PT1);
    red<<<316, 256, 0, stream>>>(PT1, 64, T1);
    gemm_bt_t<4><<<ggrid, 256, 0, stream>>>(A2, T1, PT2);
    red<<<316, 256, 0, stream>>>(PT2, 64, T2);
    cellmm<<<79, 256, 0, stream>>>(hxrow, T1, T2,
        Htin + (size_t)t * P, Ts1 + (size_t)t * P, Ts2 + (size_t)t * P,
        (u16*)nullptr, (u16*)nullptr, Wt_eg, bias_eg, 8, 0,
        hx, ub, (float*)nullptr, rhrow, HtR);
    gemm_bt_t<4><<<ggrid, 256, 0, stream>>>(A2, HtR, PT1);
    red<<<316, 256, 0, stream>>>(PT1, 64, T1);
    gemm_bt_t<4><<<ggrid, 256, 0, stream>>>(A2, T1, PT2);
    red<<<316, 256, 0, stream>>>(PT2, 64, T2);
    cellmm<<<79, 256, 0, stream>>>(rhrow, T1, T2,
        Htin + (size_t)t * P, Ts1 + (size_t)t * P, Ts2 + (size_t)t * P,
        (u16*)nullptr, (u16*)nullptr, Wt_ec, bias_ec, 4, 1,
        hx, ub, hx, hxrow, Ht1);
  }
  for (int t = 0; t < 12; t++) {
    gemm_bt_t<5><<<ggrid, 256, 0, stream>>>(A2, Ht1, PT1);
    red<<<395, 256, 0, stream>>>(PT1, 80, T1);
    gemm_bt_t<5><<<ggrid, 256, 0, stream>>>(A2, T1, PT2);
    red<<<395, 256, 0, stream>>>(PT2, 80, T2);
    cellmm<<<79, 256, 0, stream>>>(hxrow, T1, T2,
        xrow, T1 + (size_t)64 * P, T2 + (size_t)64 * P,
        sdec, sdec + P, Wt_dg, bg_d, 8, 0,
        hx, ub, (float*)nullptr, rhrow, HtR);
    gemm_bt_t<4><<<ggrid, 256, 0, stream>>>(A2, HtR, PT1);
    red<<<316, 256, 0, stream>>>(PT1, 64, T1);
    gemm_bt_t<4><<<ggrid, 256, 0, stream>>>(A2, T1, PT2);
    red<<<316, 256, 0, stream>>>(PT2, 64, T2);
    cellmm<<<79, 256, 0, stream>>>(rhrow, T1, T2,
        xrow, sdec, sdec + P,
        (u16*)nullptr, (u16*)nullptr, Wt_dc, bc_d, 4, 1,
        hx, ub, hx, hxrow, Ht1);
    pred_k<<<40, 256, 0, stream>>>(hx, W_pred, b_pred, out, xrow, Ht1, t);
  }
}